// Round 6
// baseline (615.107 us; speedup 1.0000x reference)
//
#include <hip/hip_runtime.h>

#define NNODES 100000
#define NEDGES 1250000
#define IN_CH 128
#define HID 64
#define BN_EPS 1e-5f

#define NPAD 100352               // NNODES rounded to 256 multiple (392*256)
#define NPART 8                   // edge partitions ~ XCDs
#define CNT2_LEN (NPART * NPAD)   // 802816
#define SCAN_BLOCKS (CNT2_LEN / 256)  // 3136
#define EDGE_BLOCKS ((NEDGES + 255) / 256)  // 4883; partition of edge e = (e>>8)&7

// bf16 <-> f32 helpers (bit-level, no __hip_bfloat16 class dependence)
__device__ __forceinline__ ushort f2bf(float f) {
    union { float f; unsigned int i; } c;
    c.f = f;
    unsigned int lsb = (c.i >> 16) & 1u;
    return (ushort)((c.i + 0x7FFFu + lsb) >> 16);   // round-to-nearest-even
}
__device__ __forceinline__ float bf2f(ushort u) {
    union { unsigned int i; float f; } c;
    c.i = (unsigned int)u << 16;
    return c.f;
}

// ---------------- partitioned CSR build ----------------
__global__ void csr_zero(int* cnt2) {
    int i = blockIdx.x * blockDim.x + threadIdx.x;
    if (i < CNT2_LEN) cnt2[i] = 0;
}

// partition p = (e>>8)&7 == blockIdx&7: counts land in XCD-local counter region
__global__ void csr_count(const int* __restrict__ dst, int* cnt2) {
    int e = blockIdx.x * blockDim.x + threadIdx.x;
    if (e < NEDGES) {
        int p = (e >> 8) & 7;
        atomicAdd(&cnt2[p * NPAD + dst[e]], 1);
    }
}

// dis[i] = rsqrt(1 + total degree) from the 8 per-partition counts
__global__ void make_dis(const int* __restrict__ cnt2, float* __restrict__ dis) {
    int i = blockIdx.x * blockDim.x + threadIdx.x;
    if (i >= NNODES) return;
    int s = 1;
#pragma unroll
    for (int p = 0; p < NPART; ++p) s += cnt2[p * NPAD + i];
    dis[i] = rsqrtf((float)s);
}

// per-256-block exclusive scan of cnt2 -> row_ptr2, block sums -> bsum
__global__ void scan1(const int* __restrict__ cnt2, int* __restrict__ row_ptr2,
                      int* __restrict__ bsum) {
    __shared__ int s[256];
    int tid = threadIdx.x;
    int i = blockIdx.x * 256 + tid;
    int v = cnt2[i];
    s[tid] = v;
    __syncthreads();
    for (int off = 1; off < 256; off <<= 1) {
        int t = (tid >= off) ? s[tid - off] : 0;
        __syncthreads();
        s[tid] += t;
        __syncthreads();
    }
    row_ptr2[i] = s[tid] - v;                         // exclusive within block
    if (tid == 255) bsum[blockIdx.x] = s[255];        // block total
}

// single-block exclusive scan of SCAN_BLOCKS block sums (chunked, carry loop)
__global__ void scan2(int* bsum) {
    __shared__ int s[1024];
    __shared__ int carry_s;
    int tid = threadIdx.x;
    if (tid == 0) carry_s = 0;
    __syncthreads();
    for (int base = 0; base < SCAN_BLOCKS; base += 1024) {
        int idx = base + tid;
        int v = (idx < SCAN_BLOCKS) ? bsum[idx] : 0;
        s[tid] = v;
        __syncthreads();
        for (int off = 1; off < 1024; off <<= 1) {
            int t = (tid >= off) ? s[tid - off] : 0;
            __syncthreads();
            s[tid] += t;
            __syncthreads();
        }
        int carry = carry_s;
        if (idx < SCAN_BLOCKS) bsum[idx] = s[tid] - v + carry;
        __syncthreads();
        if (tid == 0) carry_s = carry + s[1023];
        __syncthreads();
    }
}

__global__ void scan3(int* __restrict__ row_ptr2, const int* __restrict__ bsum,
                      int* __restrict__ pos2) {
    int i = blockIdx.x * blockDim.x + threadIdx.x;
    if (i < CNT2_LEN) {
        int v = row_ptr2[i] + bsum[i >> 8];
        row_ptr2[i] = v;
        pos2[i] = v;
    }
}

// partition p = blockIdx&7 ~ XCD id (round-robin dispatch): partition p's
// srcs region is written (almost) only from XCD p -> L2 merges full lines.
__global__ void csr_fill(const int* __restrict__ src, const int* __restrict__ dst,
                         int* pos2, int* __restrict__ srcs) {
    int e = blockIdx.x * blockDim.x + threadIdx.x;
    if (e < NEDGES) {
        int p = (e >> 8) & 7;
        int slot = atomicAdd(&pos2[p * NPAD + dst[e]], 1);
        srcs[slot] = src[e];
    }
}

// ---------------- fc + bn0 + relu (register-tiled 4 nodes x 4 outputs) ----
__global__ __launch_bounds__(256) void fc_bn_relu(
        const float* __restrict__ x, const float* __restrict__ w,
        const float* __restrict__ b,
        const float* __restrict__ g, const float* __restrict__ be,
        const float* __restrict__ mu, const float* __restrict__ var,
        float* __restrict__ h0) {
    const int jg = threadIdx.x & 15;          // output group: j = 4*jg .. 4*jg+3
    const int ig = threadIdx.x >> 4;          // node group within block
    const int ibase = blockIdx.x * 64 + ig * 4;
    const int j4 = jg * 4;

    float4 acc0 = {0,0,0,0}, acc1 = {0,0,0,0}, acc2 = {0,0,0,0}, acc3 = {0,0,0,0};

    int i0 = (ibase + 0 < NNODES) ? ibase + 0 : NNODES - 1;
    int i1 = (ibase + 1 < NNODES) ? ibase + 1 : NNODES - 1;
    int i2 = (ibase + 2 < NNODES) ? ibase + 2 : NNODES - 1;
    int i3 = (ibase + 3 < NNODES) ? ibase + 3 : NNODES - 1;
    const float4* x0 = (const float4*)(x + (size_t)i0 * IN_CH);
    const float4* x1 = (const float4*)(x + (size_t)i1 * IN_CH);
    const float4* x2 = (const float4*)(x + (size_t)i2 * IN_CH);
    const float4* x3 = (const float4*)(x + (size_t)i3 * IN_CH);
    const float4* w4 = (const float4*)w;      // index: k*16 + jg

#pragma unroll 8
    for (int k4 = 0; k4 < IN_CH / 4; ++k4) {
        float4 wv0 = w4[(4*k4 + 0) * 16 + jg];
        float4 wv1 = w4[(4*k4 + 1) * 16 + jg];
        float4 wv2 = w4[(4*k4 + 2) * 16 + jg];
        float4 wv3 = w4[(4*k4 + 3) * 16 + jg];
        float4 xv;
#define ROW(xr, accr) \
        xv = xr[k4]; \
        accr.x = fmaf(xv.x, wv0.x, accr.x); accr.y = fmaf(xv.x, wv0.y, accr.y); \
        accr.z = fmaf(xv.x, wv0.z, accr.z); accr.w = fmaf(xv.x, wv0.w, accr.w); \
        accr.x = fmaf(xv.y, wv1.x, accr.x); accr.y = fmaf(xv.y, wv1.y, accr.y); \
        accr.z = fmaf(xv.y, wv1.z, accr.z); accr.w = fmaf(xv.y, wv1.w, accr.w); \
        accr.x = fmaf(xv.z, wv2.x, accr.x); accr.y = fmaf(xv.z, wv2.y, accr.y); \
        accr.z = fmaf(xv.z, wv2.z, accr.z); accr.w = fmaf(xv.z, wv2.w, accr.w); \
        accr.x = fmaf(xv.w, wv3.x, accr.x); accr.y = fmaf(xv.w, wv3.y, accr.y); \
        accr.z = fmaf(xv.w, wv3.z, accr.z); accr.w = fmaf(xv.w, wv3.w, accr.w);
        ROW(x0, acc0) ROW(x1, acc1) ROW(x2, acc2) ROW(x3, acc3)
#undef ROW
    }

    float4 bv  = *(const float4*)(b + j4);
    float4 gv  = *(const float4*)(g + j4);
    float4 bev = *(const float4*)(be + j4);
    float4 muv = *(const float4*)(mu + j4);
    float4 vav = *(const float4*)(var + j4);
    float4 sc;
    sc.x = gv.x * rsqrtf(vav.x + BN_EPS);
    sc.y = gv.y * rsqrtf(vav.y + BN_EPS);
    sc.z = gv.z * rsqrtf(vav.z + BN_EPS);
    sc.w = gv.w * rsqrtf(vav.w + BN_EPS);

#define EPI(accr, r) \
    if (ibase + r < NNODES) { \
        float4 v; \
        v.x = fmaxf((accr.x + bv.x - muv.x) * sc.x + bev.x, 0.f); \
        v.y = fmaxf((accr.y + bv.y - muv.y) * sc.y + bev.y, 0.f); \
        v.z = fmaxf((accr.z + bv.z - muv.z) * sc.z + bev.z, 0.f); \
        v.w = fmaxf((accr.w + bv.w - muv.w) * sc.w + bev.w, 0.f); \
        *(float4*)(h0 + (size_t)(ibase + r) * HID + j4) = v; \
    }
    EPI(acc0, 0) EPI(acc1, 1) EPI(acc2, 2) EPI(acc3, 3)
#undef EPI
}

// ---------------- conv matmul + source-side dis scale (register-tiled) ----
// hws[i][j] = bf16( dis[i] * sum_k h[i][k] * w[k][j] )
__global__ __launch_bounds__(256) void conv_mm(
        const float* __restrict__ h, const float* __restrict__ w,
        const float* __restrict__ dis, ushort* __restrict__ hws) {
    const int jg = threadIdx.x & 15;
    const int ig = threadIdx.x >> 4;
    const int ibase = blockIdx.x * 64 + ig * 4;
    const int j4 = jg * 4;

    float4 acc0 = {0,0,0,0}, acc1 = {0,0,0,0}, acc2 = {0,0,0,0}, acc3 = {0,0,0,0};

    int i0 = (ibase + 0 < NNODES) ? ibase + 0 : NNODES - 1;
    int i1 = (ibase + 1 < NNODES) ? ibase + 1 : NNODES - 1;
    int i2 = (ibase + 2 < NNODES) ? ibase + 2 : NNODES - 1;
    int i3 = (ibase + 3 < NNODES) ? ibase + 3 : NNODES - 1;
    const float4* h0p = (const float4*)(h + (size_t)i0 * HID);
    const float4* h1p = (const float4*)(h + (size_t)i1 * HID);
    const float4* h2p = (const float4*)(h + (size_t)i2 * HID);
    const float4* h3p = (const float4*)(h + (size_t)i3 * HID);
    const float4* w4 = (const float4*)w;

#pragma unroll 8
    for (int k4 = 0; k4 < HID / 4; ++k4) {
        float4 wv0 = w4[(4*k4 + 0) * 16 + jg];
        float4 wv1 = w4[(4*k4 + 1) * 16 + jg];
        float4 wv2 = w4[(4*k4 + 2) * 16 + jg];
        float4 wv3 = w4[(4*k4 + 3) * 16 + jg];
        float4 xv;
#define ROW(xr, accr) \
        xv = xr[k4]; \
        accr.x = fmaf(xv.x, wv0.x, accr.x); accr.y = fmaf(xv.x, wv0.y, accr.y); \
        accr.z = fmaf(xv.x, wv0.z, accr.z); accr.w = fmaf(xv.x, wv0.w, accr.w); \
        accr.x = fmaf(xv.y, wv1.x, accr.x); accr.y = fmaf(xv.y, wv1.y, accr.y); \
        accr.z = fmaf(xv.y, wv1.z, accr.z); accr.w = fmaf(xv.y, wv1.w, accr.w); \
        accr.x = fmaf(xv.z, wv2.x, accr.x); accr.y = fmaf(xv.z, wv2.y, accr.y); \
        accr.z = fmaf(xv.z, wv2.z, accr.z); accr.w = fmaf(xv.z, wv2.w, accr.w); \
        accr.x = fmaf(xv.w, wv3.x, accr.x); accr.y = fmaf(xv.w, wv3.y, accr.y); \
        accr.z = fmaf(xv.w, wv3.z, accr.z); accr.w = fmaf(xv.w, wv3.w, accr.w);
        ROW(h0p, acc0) ROW(h1p, acc1) ROW(h2p, acc2) ROW(h3p, acc3)
#undef ROW
    }

#define EPI(accr, ir, r) \
    if (ibase + r < NNODES) { \
        float dv = dis[ir]; \
        ushort4 o; \
        o.x = f2bf(accr.x * dv); \
        o.y = f2bf(accr.y * dv); \
        o.z = f2bf(accr.z * dv); \
        o.w = f2bf(accr.w * dv); \
        *(ushort4*)(hws + (size_t)(ibase + r) * HID + j4) = o; \
    }
    EPI(acc0, i0, 0) EPI(acc1, i1, 1) EPI(acc2, i2, 2) EPI(acc3, i3, 3)
#undef EPI
}

// ---------------- gather + epilogue (one wave per dst node) ----------------
// agg_j = hws[d][j] (self loop) + sum over 8 partition segments of incoming srcs
__global__ void gather_update(const ushort* __restrict__ hws,
                              const int* __restrict__ row_ptr2, const int* __restrict__ cnt2,
                              const int* __restrict__ srcs, const float* __restrict__ dis,
                              const float* __restrict__ bias,
                              const float* __restrict__ g, const float* __restrict__ be,
                              const float* __restrict__ mu, const float* __restrict__ var,
                              const float* __restrict__ last, float* __restrict__ hout) {
    int t = blockIdx.x * blockDim.x + threadIdx.x;
    int d = t >> 6;
    if (d >= NNODES) return;
    int j = t & 63;

    float acc = bf2f(hws[(size_t)d * HID + j]);   // self-loop

#pragma unroll
    for (int p = 0; p < NPART; ++p) {
        int start = row_ptr2[p * NPAD + d];
        int n = cnt2[p * NPAD + d];
        const int* sp = srcs + start;
        int k = 0;
        for (; k + 3 < n; k += 4) {               // unroll 4 for load ILP
            int s0 = sp[k + 0], s1 = sp[k + 1], s2 = sp[k + 2], s3 = sp[k + 3];
            float v0 = bf2f(hws[(size_t)s0 * HID + j]);
            float v1 = bf2f(hws[(size_t)s1 * HID + j]);
            float v2 = bf2f(hws[(size_t)s2 * HID + j]);
            float v3 = bf2f(hws[(size_t)s3 * HID + j]);
            acc += v0 + v1 + v2 + v3;
        }
        for (; k < n; ++k) acc += bf2f(hws[(size_t)sp[k] * HID + j]);
    }

    float v = acc * dis[d] + bias[j];
    v = (v - mu[j]) * (g[j] * rsqrtf(var[j] + BN_EPS)) + be[j];
    hout[(size_t)d * HID + j] = fmaxf(v, 0.f) + last[(size_t)d * HID + j];
}

extern "C" void kernel_launch(void* const* d_in, const int* in_sizes, int n_in,
                              void* d_out, int out_size, void* d_ws, size_t ws_size,
                              hipStream_t stream) {
    const float* x      = (const float*)d_in[0];
    const int*   eidx   = (const int*)d_in[1];
    const float* fc_w   = (const float*)d_in[2];
    const float* fc_b   = (const float*)d_in[3];
    const float* conv_w = (const float*)d_in[4];
    const float* conv_b = (const float*)d_in[5];
    const float* bn_g   = (const float*)d_in[6];
    const float* bn_b   = (const float*)d_in[7];
    const float* bn_m   = (const float*)d_in[8];
    const float* bn_v   = (const float*)d_in[9];

    const int* src = eidx;
    const int* dst = eidx + NEDGES;

    float* hio = (float*)d_out;       // serves as h1 (layer-1 out) and final out

    // workspace (4B elems): dis | cnt2 | row_ptr2 | pos2 | bsum | srcs | h0 | hws(bf16)
    float*  dis      = (float*)d_ws;
    int*    cnt2     = (int*)(dis + NPAD);
    int*    row_ptr2 = cnt2 + CNT2_LEN;
    int*    pos2     = row_ptr2 + CNT2_LEN;
    int*    bsum     = pos2 + CNT2_LEN;
    int*    srcs     = bsum + 4096;
    float*  h0       = (float*)(srcs + NEDGES) + 48;   // re-align; residual `last`
    ushort* hws      = (ushort*)(h0 + (size_t)NNODES * HID);

    const int BLK = 256;
    const int gridN  = (NNODES + BLK - 1) / BLK;
    const int gridC  = (CNT2_LEN + BLK - 1) / BLK;       // 3136
    const int gridNH = (NNODES * HID + BLK - 1) / BLK;   // 25000 (gather)
    const int gridMM = (NNODES + 63) / 64;               // 1563 (tiled matmuls)

    // partitioned CSR build + degree
    csr_zero<<<gridC, BLK, 0, stream>>>(cnt2);
    csr_count<<<EDGE_BLOCKS, BLK, 0, stream>>>(dst, cnt2);
    make_dis<<<gridN, BLK, 0, stream>>>(cnt2, dis);
    scan1<<<SCAN_BLOCKS, 256, 0, stream>>>(cnt2, row_ptr2, bsum);
    scan2<<<1, 1024, 0, stream>>>(bsum);
    scan3<<<gridC, BLK, 0, stream>>>(row_ptr2, bsum, pos2);
    csr_fill<<<EDGE_BLOCKS, BLK, 0, stream>>>(src, dst, pos2, srcs);

    // fc + bn0 + relu -> h0 (residual). h0 is never overwritten.
    fc_bn_relu<<<gridMM, BLK, 0, stream>>>(x, fc_w, fc_b, bn_g, bn_b, bn_m, bn_v, h0);

    // layer 1: h0 -> hws -> hio
    conv_mm<<<gridMM, BLK, 0, stream>>>(h0, conv_w, dis, hws);
    gather_update<<<gridNH, BLK, 0, stream>>>(hws, row_ptr2, cnt2, srcs, dis,
                                              conv_b, bn_g + HID, bn_b + HID,
                                              bn_m + HID, bn_v + HID, h0, hio);

    // layer 2: hio -> hws -> hio (final output)
    conv_mm<<<gridMM, BLK, 0, stream>>>(hio, conv_w + HID * HID, dis, hws);
    gather_update<<<gridNH, BLK, 0, stream>>>(hws, row_ptr2, cnt2, srcs, dis,
                                              conv_b + HID, bn_g + 2 * HID, bn_b + 2 * HID,
                                              bn_m + 2 * HID, bn_v + 2 * HID, h0, hio);
}

// Round 7
// 478.329 us; speedup vs baseline: 1.2860x; 1.2860x over previous
//
#include <hip/hip_runtime.h>

#define NNODES 100000
#define NEDGES 1250000
#define IN_CH 128
#define HID 64
#define BN_EPS 1e-5f

#define NPAD 100352               // NNODES rounded to 256 multiple
#define NSCAN_BLOCKS 391          // ceil(100000/256)
#define DRANGE 12500              // NNODES / 8 (dst range per XCD)
#define FILL_CHUNK 2048           // edges per block in filtered count/fill
#define FILL_CHUNKS 611           // ceil(NEDGES / FILL_CHUNK)
#define GGROUPS 12500             // gather node groups (8 nodes each)

// bf16 <-> f32 helpers (bit-level, no __hip_bfloat16 class dependence)
__device__ __forceinline__ ushort f2bf(float f) {
    union { float f; unsigned int i; } c;
    c.f = f;
    unsigned int lsb = (c.i >> 16) & 1u;
    return (ushort)((c.i + 0x7FFFu + lsb) >> 16);   // round-to-nearest-even
}
__device__ __forceinline__ float bf2f(ushort u) {
    union { unsigned int i; float f; } c;
    c.i = (unsigned int)u << 16;
    return c.f;
}

// ---------------- CSR build (dst-range partitioned by XCD) ----------------
__global__ void csr_zero(int* cnt) {
    int i = blockIdx.x * blockDim.x + threadIdx.x;
    if (i < NNODES) cnt[i] = 0;
}

// block b -> XCD b&7 (round-robin dispatch heuristic) -> dst range
// [p*DRANGE, (p+1)*DRANGE). Each XCD streams the whole dst[] (redundant reads
// served by L2/L3) but its atomic lines stay XCD-local.
__global__ void csr_count(const int* __restrict__ dst, int* cnt) {
    int p = blockIdx.x & 7;
    int base = (blockIdx.x >> 3) * FILL_CHUNK;
    int lo = p * DRANGE, hi = lo + DRANGE;
#pragma unroll
    for (int k = 0; k < FILL_CHUNK / 256; ++k) {
        int e = base + k * 256 + threadIdx.x;
        if (e < NEDGES) {
            int d = dst[e];
            if (d >= lo && d < hi) atomicAdd(&cnt[d], 1);
        }
    }
}

// per-256-block exclusive scan of cnt -> row_ptr, block sums -> bsum.
// Also emits dis[i] = rsqrt(cnt[i]+1)  (degree incl. self-loop).
__global__ void scan1(const int* __restrict__ cnt, int* __restrict__ row_ptr,
                      int* __restrict__ bsum, float* __restrict__ dis) {
    __shared__ int s[256];
    int tid = threadIdx.x;
    int i = blockIdx.x * 256 + tid;
    int v = (i < NNODES) ? cnt[i] : 0;
    if (i < NNODES) dis[i] = rsqrtf((float)(v + 1));
    s[tid] = v;
    __syncthreads();
    for (int off = 1; off < 256; off <<= 1) {
        int t = (tid >= off) ? s[tid - off] : 0;
        __syncthreads();
        s[tid] += t;
        __syncthreads();
    }
    if (i < NNODES) row_ptr[i] = s[tid] - v;          // exclusive
    if (tid == 255) bsum[blockIdx.x] = s[255];        // block total
}

// single-block exclusive scan of the 391 block sums (512 threads, padded)
__global__ void scan2(int* bsum) {
    __shared__ int s[512];
    int tid = threadIdx.x;
    int v = (tid < NSCAN_BLOCKS) ? bsum[tid] : 0;
    s[tid] = v;
    __syncthreads();
    for (int off = 1; off < 512; off <<= 1) {
        int t = (tid >= off) ? s[tid - off] : 0;
        __syncthreads();
        s[tid] += t;
        __syncthreads();
    }
    if (tid < NSCAN_BLOCKS) bsum[tid] = s[tid] - v;   // exclusive
}

__global__ void scan3(int* __restrict__ row_ptr, const int* __restrict__ bsum,
                      int* __restrict__ pos) {
    int i = blockIdx.x * blockDim.x + threadIdx.x;
    if (i < NNODES) {
        int v = row_ptr[i] + bsum[i >> 8];
        row_ptr[i] = v;
        pos[i] = v;
    }
}

// Same dst-range filtering: XCD p only writes srcs slots belonging to its dst
// range -> contiguous ~640 KB region, fully merged in its local L2.
__global__ void csr_fill(const int* __restrict__ src, const int* __restrict__ dst,
                         int* pos, int* __restrict__ srcs) {
    int p = blockIdx.x & 7;
    int base = (blockIdx.x >> 3) * FILL_CHUNK;
    int lo = p * DRANGE, hi = lo + DRANGE;
#pragma unroll
    for (int k = 0; k < FILL_CHUNK / 256; ++k) {
        int e = base + k * 256 + threadIdx.x;
        if (e < NEDGES) {
            int d = dst[e];
            if (d >= lo && d < hi) {
                int slot = atomicAdd(&pos[d], 1);
                srcs[slot] = src[e];
            }
        }
    }
}

// ---------------- fc + bn0 + relu (register-tiled 4 nodes x 4 outputs) ----
__global__ __launch_bounds__(256) void fc_bn_relu(
        const float* __restrict__ x, const float* __restrict__ w,
        const float* __restrict__ b,
        const float* __restrict__ g, const float* __restrict__ be,
        const float* __restrict__ mu, const float* __restrict__ var,
        float* __restrict__ h0) {
    const int jg = threadIdx.x & 15;          // output group: j = 4*jg .. 4*jg+3
    const int ig = threadIdx.x >> 4;          // node group within block
    const int ibase = blockIdx.x * 64 + ig * 4;
    const int j4 = jg * 4;

    float4 acc0 = {0,0,0,0}, acc1 = {0,0,0,0}, acc2 = {0,0,0,0}, acc3 = {0,0,0,0};

    int i0 = (ibase + 0 < NNODES) ? ibase + 0 : NNODES - 1;
    int i1 = (ibase + 1 < NNODES) ? ibase + 1 : NNODES - 1;
    int i2 = (ibase + 2 < NNODES) ? ibase + 2 : NNODES - 1;
    int i3 = (ibase + 3 < NNODES) ? ibase + 3 : NNODES - 1;
    const float4* x0 = (const float4*)(x + (size_t)i0 * IN_CH);
    const float4* x1 = (const float4*)(x + (size_t)i1 * IN_CH);
    const float4* x2 = (const float4*)(x + (size_t)i2 * IN_CH);
    const float4* x3 = (const float4*)(x + (size_t)i3 * IN_CH);
    const float4* w4 = (const float4*)w;      // index: k*16 + jg

#pragma unroll 8
    for (int k4 = 0; k4 < IN_CH / 4; ++k4) {
        float4 wv0 = w4[(4*k4 + 0) * 16 + jg];
        float4 wv1 = w4[(4*k4 + 1) * 16 + jg];
        float4 wv2 = w4[(4*k4 + 2) * 16 + jg];
        float4 wv3 = w4[(4*k4 + 3) * 16 + jg];
        float4 xv;
#define ROW(xr, accr) \
        xv = xr[k4]; \
        accr.x = fmaf(xv.x, wv0.x, accr.x); accr.y = fmaf(xv.x, wv0.y, accr.y); \
        accr.z = fmaf(xv.x, wv0.z, accr.z); accr.w = fmaf(xv.x, wv0.w, accr.w); \
        accr.x = fmaf(xv.y, wv1.x, accr.x); accr.y = fmaf(xv.y, wv1.y, accr.y); \
        accr.z = fmaf(xv.y, wv1.z, accr.z); accr.w = fmaf(xv.y, wv1.w, accr.w); \
        accr.x = fmaf(xv.z, wv2.x, accr.x); accr.y = fmaf(xv.z, wv2.y, accr.y); \
        accr.z = fmaf(xv.z, wv2.z, accr.z); accr.w = fmaf(xv.z, wv2.w, accr.w); \
        accr.x = fmaf(xv.w, wv3.x, accr.x); accr.y = fmaf(xv.w, wv3.y, accr.y); \
        accr.z = fmaf(xv.w, wv3.z, accr.z); accr.w = fmaf(xv.w, wv3.w, accr.w);
        ROW(x0, acc0) ROW(x1, acc1) ROW(x2, acc2) ROW(x3, acc3)
#undef ROW
    }

    float4 bv  = *(const float4*)(b + j4);
    float4 gv  = *(const float4*)(g + j4);
    float4 bev = *(const float4*)(be + j4);
    float4 muv = *(const float4*)(mu + j4);
    float4 vav = *(const float4*)(var + j4);
    float4 sc;
    sc.x = gv.x * rsqrtf(vav.x + BN_EPS);
    sc.y = gv.y * rsqrtf(vav.y + BN_EPS);
    sc.z = gv.z * rsqrtf(vav.z + BN_EPS);
    sc.w = gv.w * rsqrtf(vav.w + BN_EPS);

#define EPI(accr, r) \
    if (ibase + r < NNODES) { \
        float4 v; \
        v.x = fmaxf((accr.x + bv.x - muv.x) * sc.x + bev.x, 0.f); \
        v.y = fmaxf((accr.y + bv.y - muv.y) * sc.y + bev.y, 0.f); \
        v.z = fmaxf((accr.z + bv.z - muv.z) * sc.z + bev.z, 0.f); \
        v.w = fmaxf((accr.w + bv.w - muv.w) * sc.w + bev.w, 0.f); \
        *(float4*)(h0 + (size_t)(ibase + r) * HID + j4) = v; \
    }
    EPI(acc0, 0) EPI(acc1, 1) EPI(acc2, 2) EPI(acc3, 3)
#undef EPI
}

// ---------------- conv matmul + source-side dis scale (register-tiled) ----
// hws[i][j] = bf16( dis[i] * sum_k h[i][k] * w[k][j] )
__global__ __launch_bounds__(256) void conv_mm(
        const float* __restrict__ h, const float* __restrict__ w,
        const float* __restrict__ dis, ushort* __restrict__ hws) {
    const int jg = threadIdx.x & 15;
    const int ig = threadIdx.x >> 4;
    const int ibase = blockIdx.x * 64 + ig * 4;
    const int j4 = jg * 4;

    float4 acc0 = {0,0,0,0}, acc1 = {0,0,0,0}, acc2 = {0,0,0,0}, acc3 = {0,0,0,0};

    int i0 = (ibase + 0 < NNODES) ? ibase + 0 : NNODES - 1;
    int i1 = (ibase + 1 < NNODES) ? ibase + 1 : NNODES - 1;
    int i2 = (ibase + 2 < NNODES) ? ibase + 2 : NNODES - 1;
    int i3 = (ibase + 3 < NNODES) ? ibase + 3 : NNODES - 1;
    const float4* h0p = (const float4*)(h + (size_t)i0 * HID);
    const float4* h1p = (const float4*)(h + (size_t)i1 * HID);
    const float4* h2p = (const float4*)(h + (size_t)i2 * HID);
    const float4* h3p = (const float4*)(h + (size_t)i3 * HID);
    const float4* w4 = (const float4*)w;

#pragma unroll 8
    for (int k4 = 0; k4 < HID / 4; ++k4) {
        float4 wv0 = w4[(4*k4 + 0) * 16 + jg];
        float4 wv1 = w4[(4*k4 + 1) * 16 + jg];
        float4 wv2 = w4[(4*k4 + 2) * 16 + jg];
        float4 wv3 = w4[(4*k4 + 3) * 16 + jg];
        float4 xv;
#define ROW(xr, accr) \
        xv = xr[k4]; \
        accr.x = fmaf(xv.x, wv0.x, accr.x); accr.y = fmaf(xv.x, wv0.y, accr.y); \
        accr.z = fmaf(xv.x, wv0.z, accr.z); accr.w = fmaf(xv.x, wv0.w, accr.w); \
        accr.x = fmaf(xv.y, wv1.x, accr.x); accr.y = fmaf(xv.y, wv1.y, accr.y); \
        accr.z = fmaf(xv.y, wv1.z, accr.z); accr.w = fmaf(xv.y, wv1.w, accr.w); \
        accr.x = fmaf(xv.z, wv2.x, accr.x); accr.y = fmaf(xv.z, wv2.y, accr.y); \
        accr.z = fmaf(xv.z, wv2.z, accr.z); accr.w = fmaf(xv.z, wv2.w, accr.w); \
        accr.x = fmaf(xv.w, wv3.x, accr.x); accr.y = fmaf(xv.w, wv3.y, accr.y); \
        accr.z = fmaf(xv.w, wv3.z, accr.z); accr.w = fmaf(xv.w, wv3.w, accr.w);
        ROW(h0p, acc0) ROW(h1p, acc1) ROW(h2p, acc2) ROW(h3p, acc3)
#undef ROW
    }

#define EPI(accr, ir, r) \
    if (ibase + r < NNODES) { \
        float dv = dis[ir]; \
        ushort4 o; \
        o.x = f2bf(accr.x * dv); \
        o.y = f2bf(accr.y * dv); \
        o.z = f2bf(accr.z * dv); \
        o.w = f2bf(accr.w * dv); \
        *(ushort4*)(hws + (size_t)(ibase + r) * HID + j4) = o; \
    }
    EPI(acc0, i0, 0) EPI(acc1, i1, 1) EPI(acc2, i2, 2) EPI(acc3, i3, 3)
#undef EPI
}

// ---------------- gather + epilogue (column-sliced by XCD) ----------------
// Block b: slice = ((b&7)>=4) -> columns [slice*32, slice*32+32) = one 64B
// line of each bf16 row. XCDs 0-3 handle slice 0, XCDs 4-7 slice 1 (b%8 ~ XCD
// round-robin heuristic): each XCD touches only one line per source row.
// Wave = 2 nodes x 32 cols; block of 256 = 8 nodes.
__global__ void gather_update(const ushort* __restrict__ hws,
                              const int* __restrict__ row_ptr, const int* __restrict__ cnt,
                              const int* __restrict__ srcs, const float* __restrict__ dis,
                              const float* __restrict__ bias,
                              const float* __restrict__ g, const float* __restrict__ be,
                              const float* __restrict__ mu, const float* __restrict__ var,
                              const float* __restrict__ last, float* __restrict__ hout) {
    int b = blockIdx.x;
    int slice = (b >> 2) & 1;                       // == ((b&7) >= 4)
    int group = ((b >> 3) << 2) | (b & 3);          // [0, GGROUPS)
    int wave = threadIdx.x >> 6;
    int lane = threadIdx.x & 63;
    int d = group * 8 + wave * 2 + (lane >> 5);
    if (d >= NNODES) return;
    int col = slice * 32 + (lane & 31);

    float acc = bf2f(hws[(size_t)d * HID + col]);   // self-loop
    int start = row_ptr[d];
    int n = cnt[d];
    const int* sp = srcs + start;

    int k = 0;
    for (; k + 3 < n; k += 4) {                     // unroll 4 for load ILP
        int s0 = sp[k + 0], s1 = sp[k + 1], s2 = sp[k + 2], s3 = sp[k + 3];
        float v0 = bf2f(hws[(size_t)s0 * HID + col]);
        float v1 = bf2f(hws[(size_t)s1 * HID + col]);
        float v2 = bf2f(hws[(size_t)s2 * HID + col]);
        float v3 = bf2f(hws[(size_t)s3 * HID + col]);
        acc += v0 + v1 + v2 + v3;
    }
    for (; k < n; ++k) acc += bf2f(hws[(size_t)sp[k] * HID + col]);

    float v = acc * dis[d] + bias[col];
    v = (v - mu[col]) * (g[col] * rsqrtf(var[col] + BN_EPS)) + be[col];
    hout[(size_t)d * HID + col] = fmaxf(v, 0.f) + last[(size_t)d * HID + col];
}

extern "C" void kernel_launch(void* const* d_in, const int* in_sizes, int n_in,
                              void* d_out, int out_size, void* d_ws, size_t ws_size,
                              hipStream_t stream) {
    const float* x      = (const float*)d_in[0];
    const int*   eidx   = (const int*)d_in[1];
    const float* fc_w   = (const float*)d_in[2];
    const float* fc_b   = (const float*)d_in[3];
    const float* conv_w = (const float*)d_in[4];
    const float* conv_b = (const float*)d_in[5];
    const float* bn_g   = (const float*)d_in[6];
    const float* bn_b   = (const float*)d_in[7];
    const float* bn_m   = (const float*)d_in[8];
    const float* bn_v   = (const float*)d_in[9];

    const int* src = eidx;
    const int* dst = eidx + NEDGES;

    float* hio = (float*)d_out;       // serves as h1 (layer-1 out) and final out

    // workspace (4B elems): dis | cnt | row_ptr | pos | bsum | srcs | h0 | hws(bf16)
    float*  dis     = (float*)d_ws;
    int*    cnt     = (int*)(dis + NPAD);
    int*    row_ptr = cnt + NPAD;
    int*    pos     = row_ptr + NPAD;
    int*    bsum    = pos + NPAD;
    int*    srcs    = bsum + 512;
    float*  h0      = (float*)(srcs + NEDGES) + 48;   // re-align; residual `last`
    ushort* hws     = (ushort*)(h0 + (size_t)NNODES * HID);

    const int BLK = 256;
    const int gridN   = (NNODES + BLK - 1) / BLK;
    const int gridF   = FILL_CHUNKS * 8;                 // 4888 (filtered count/fill)
    const int gridGA  = GGROUPS * 2;                     // 25000 (sliced gather)
    const int gridMM  = (NNODES + 63) / 64;              // 1563 (tiled matmuls)

    // CSR build + degree (dst-range partitioned)
    csr_zero<<<gridN, BLK, 0, stream>>>(cnt);
    csr_count<<<gridF, BLK, 0, stream>>>(dst, cnt);
    scan1<<<NSCAN_BLOCKS, 256, 0, stream>>>(cnt, row_ptr, bsum, dis);
    scan2<<<1, 512, 0, stream>>>(bsum);
    scan3<<<gridN, BLK, 0, stream>>>(row_ptr, bsum, pos);
    csr_fill<<<gridF, BLK, 0, stream>>>(src, dst, pos, srcs);

    // fc + bn0 + relu -> h0 (residual). h0 is never overwritten.
    fc_bn_relu<<<gridMM, BLK, 0, stream>>>(x, fc_w, fc_b, bn_g, bn_b, bn_m, bn_v, h0);

    // layer 1: h0 -> hws -> hio
    conv_mm<<<gridMM, BLK, 0, stream>>>(h0, conv_w, dis, hws);
    gather_update<<<gridGA, BLK, 0, stream>>>(hws, row_ptr, cnt, srcs, dis,
                                              conv_b, bn_g + HID, bn_b + HID,
                                              bn_m + HID, bn_v + HID, h0, hio);

    // layer 2: hio -> hws -> hio (final output)
    conv_mm<<<gridMM, BLK, 0, stream>>>(hio, conv_w + HID * HID, dis, hws);
    gather_update<<<gridGA, BLK, 0, stream>>>(hws, row_ptr, cnt, srcs, dis,
                                              conv_b + HID, bn_g + 2 * HID, bn_b + 2 * HID,
                                              bn_m + 2 * HID, bn_v + 2 * HID, h0, hio);
}

// Round 8
// 411.311 us; speedup vs baseline: 1.4955x; 1.1629x over previous
//
#include <hip/hip_runtime.h>

#define NNODES 100000
#define NEDGES 1250000
#define IN_CH 128
#define HID 64
#define BN_EPS 1e-5f

#define NPAD 100352               // NNODES rounded to 256 multiple
#define NSCAN_BLOCKS 391          // ceil(100000/256)
#define DRANGE 12500              // NNODES / 8 (dst range per XCD)
#define FILL_CHUNK 2048           // edges per block in filtered count/fill
#define FILL_CHUNKS 611           // ceil(NEDGES / FILL_CHUNK)
#define GGROUPS 12500             // gather node groups (8 nodes each)

typedef __attribute__((ext_vector_type(8))) short s16x8;   // 8 bf16 (4 VGPRs)
typedef __attribute__((ext_vector_type(4))) float f32x4;

// bf16 <-> f32 helpers (bit-level, no __hip_bfloat16 class dependence)
__device__ __forceinline__ ushort f2bf(float f) {
    union { float f; unsigned int i; } c;
    c.f = f;
    unsigned int lsb = (c.i >> 16) & 1u;
    return (ushort)((c.i + 0x7FFFu + lsb) >> 16);   // round-to-nearest-even
}
__device__ __forceinline__ float bf2f(ushort u) {
    union { unsigned int i; float f; } c;
    c.i = (unsigned int)u << 16;
    return c.f;
}

// ---------------- CSR build (dst-range partitioned by XCD) ----------------
__global__ void csr_zero(int* cnt) {
    int i = blockIdx.x * blockDim.x + threadIdx.x;
    if (i < NNODES) cnt[i] = 0;
}

// block b -> XCD b&7 (round-robin dispatch heuristic) -> dst range
// [p*DRANGE, (p+1)*DRANGE). Each XCD streams the whole dst[] (redundant reads
// served by L2/L3) but its atomic lines stay XCD-local.
__global__ void csr_count(const int* __restrict__ dst, int* cnt) {
    int p = blockIdx.x & 7;
    int base = (blockIdx.x >> 3) * FILL_CHUNK;
    int lo = p * DRANGE, hi = lo + DRANGE;
#pragma unroll
    for (int k = 0; k < FILL_CHUNK / 256; ++k) {
        int e = base + k * 256 + threadIdx.x;
        if (e < NEDGES) {
            int d = dst[e];
            if (d >= lo && d < hi) atomicAdd(&cnt[d], 1);
        }
    }
}

// per-256-block exclusive scan of cnt -> row_ptr, block sums -> bsum.
// Also emits dis[i] = rsqrt(cnt[i]+1)  (degree incl. self-loop).
__global__ void scan1(const int* __restrict__ cnt, int* __restrict__ row_ptr,
                      int* __restrict__ bsum, float* __restrict__ dis) {
    __shared__ int s[256];
    int tid = threadIdx.x;
    int i = blockIdx.x * 256 + tid;
    int v = (i < NNODES) ? cnt[i] : 0;
    if (i < NNODES) dis[i] = rsqrtf((float)(v + 1));
    s[tid] = v;
    __syncthreads();
    for (int off = 1; off < 256; off <<= 1) {
        int t = (tid >= off) ? s[tid - off] : 0;
        __syncthreads();
        s[tid] += t;
        __syncthreads();
    }
    if (i < NNODES) row_ptr[i] = s[tid] - v;          // exclusive
    if (tid == 255) bsum[blockIdx.x] = s[255];        // block total
}

// single-block exclusive scan of the 391 block sums (512 threads, padded)
__global__ void scan2(int* bsum) {
    __shared__ int s[512];
    int tid = threadIdx.x;
    int v = (tid < NSCAN_BLOCKS) ? bsum[tid] : 0;
    s[tid] = v;
    __syncthreads();
    for (int off = 1; off < 512; off <<= 1) {
        int t = (tid >= off) ? s[tid - off] : 0;
        __syncthreads();
        s[tid] += t;
        __syncthreads();
    }
    if (tid < NSCAN_BLOCKS) bsum[tid] = s[tid] - v;   // exclusive
}

__global__ void scan3(int* __restrict__ row_ptr, const int* __restrict__ bsum,
                      int* __restrict__ pos) {
    int i = blockIdx.x * blockDim.x + threadIdx.x;
    if (i < NNODES) {
        int v = row_ptr[i] + bsum[i >> 8];
        row_ptr[i] = v;
        pos[i] = v;
    }
}

// Same dst-range filtering: XCD p only writes srcs slots belonging to its dst
// range -> contiguous ~640 KB region, fully merged in its local L2.
__global__ void csr_fill(const int* __restrict__ src, const int* __restrict__ dst,
                         int* pos, int* __restrict__ srcs) {
    int p = blockIdx.x & 7;
    int base = (blockIdx.x >> 3) * FILL_CHUNK;
    int lo = p * DRANGE, hi = lo + DRANGE;
#pragma unroll
    for (int k = 0; k < FILL_CHUNK / 256; ++k) {
        int e = base + k * 256 + threadIdx.x;
        if (e < NEDGES) {
            int d = dst[e];
            if (d >= lo && d < hi) {
                int slot = atomicAdd(&pos[d], 1);
                srcs[slot] = src[e];
            }
        }
    }
}

// ---------------- fc + bn0 + relu (MFMA, 16 nodes x 64 cols per wave) -----
// h0[i][j] = relu(bn0(sum_k x[i][k]*w[k][j] + b[j]))
// A-frag: A[m=lane&15][k=(lane>>4)*8+j]; B-frag: B[k=(lane>>4)*8+j][n=lane&15]
// C/D: col=lane&15, row=(lane>>4)*4+reg  (per cdna_hip_programming.md §3)
__global__ __launch_bounds__(256) void fc_bn_relu(
        const float* __restrict__ x, const float* __restrict__ w,
        const float* __restrict__ b,
        const float* __restrict__ g, const float* __restrict__ be,
        const float* __restrict__ mu, const float* __restrict__ var,
        float* __restrict__ h0) {
    const int wave = threadIdx.x >> 6;
    const int lane = threadIdx.x & 63;
    const int m = lane & 15;
    const int q = lane >> 4;
    const int node_base = (blockIdx.x * 4 + wave) * 16;

    // B fragments: 4 k-chunks x 4 col-tiles (w is 128x64, L1/L2 resident)
    s16x8 bfrag[4][4];
#pragma unroll
    for (int kc = 0; kc < 4; ++kc)
#pragma unroll
        for (int ct = 0; ct < 4; ++ct)
#pragma unroll
            for (int j = 0; j < 8; ++j)
                bfrag[kc][ct][j] = (short)f2bf(w[(kc * 32 + q * 8 + j) * HID + ct * 16 + m]);

    f32x4 acc[4] = {{0,0,0,0},{0,0,0,0},{0,0,0,0},{0,0,0,0}};

    int row = node_base + m;
    if (row >= NNODES) row = NNODES - 1;             // clamp (stores guarded)
    const float4* xp = (const float4*)(x + (size_t)row * IN_CH + q * 8);

#pragma unroll
    for (int kc = 0; kc < 4; ++kc) {
        float4 a0 = xp[kc * 8 + 0];                  // k = kc*32 + q*8 + 0..3
        float4 a1 = xp[kc * 8 + 1];                  // k = kc*32 + q*8 + 4..7
        s16x8 af;
        af[0] = (short)f2bf(a0.x); af[1] = (short)f2bf(a0.y);
        af[2] = (short)f2bf(a0.z); af[3] = (short)f2bf(a0.w);
        af[4] = (short)f2bf(a1.x); af[5] = (short)f2bf(a1.y);
        af[6] = (short)f2bf(a1.z); af[7] = (short)f2bf(a1.w);
#pragma unroll
        for (int ct = 0; ct < 4; ++ct)
            acc[ct] = __builtin_amdgcn_mfma_f32_16x16x32_bf16(af, bfrag[kc][ct], acc[ct], 0, 0, 0);
    }

#pragma unroll
    for (int ct = 0; ct < 4; ++ct) {
        int col = ct * 16 + m;
        float sc = g[col] * rsqrtf(var[col] + BN_EPS);
        float off = (b[col] - mu[col]) * sc + be[col];
#pragma unroll
        for (int r = 0; r < 4; ++r) {
            int node = node_base + q * 4 + r;
            if (node < NNODES)
                h0[(size_t)node * HID + col] = fmaxf(acc[ct][r] * sc + off, 0.f);
        }
    }
}

// ---------------- conv matmul + source-side dis scale (MFMA) --------------
// hws[i][j] = bf16( dis[i] * sum_k h[i][k] * w[k][j] ),  K = 64
__global__ __launch_bounds__(256) void conv_mm(
        const float* __restrict__ h, const float* __restrict__ w,
        const float* __restrict__ dis, ushort* __restrict__ hws) {
    const int wave = threadIdx.x >> 6;
    const int lane = threadIdx.x & 63;
    const int m = lane & 15;
    const int q = lane >> 4;
    const int node_base = (blockIdx.x * 4 + wave) * 16;

    s16x8 bfrag[2][4];
#pragma unroll
    for (int kc = 0; kc < 2; ++kc)
#pragma unroll
        for (int ct = 0; ct < 4; ++ct)
#pragma unroll
            for (int j = 0; j < 8; ++j)
                bfrag[kc][ct][j] = (short)f2bf(w[(kc * 32 + q * 8 + j) * HID + ct * 16 + m]);

    f32x4 acc[4] = {{0,0,0,0},{0,0,0,0},{0,0,0,0},{0,0,0,0}};

    int row = node_base + m;
    if (row >= NNODES) row = NNODES - 1;
    const float4* hp = (const float4*)(h + (size_t)row * HID + q * 8);

#pragma unroll
    for (int kc = 0; kc < 2; ++kc) {
        float4 a0 = hp[kc * 8 + 0];
        float4 a1 = hp[kc * 8 + 1];
        s16x8 af;
        af[0] = (short)f2bf(a0.x); af[1] = (short)f2bf(a0.y);
        af[2] = (short)f2bf(a0.z); af[3] = (short)f2bf(a0.w);
        af[4] = (short)f2bf(a1.x); af[5] = (short)f2bf(a1.y);
        af[6] = (short)f2bf(a1.z); af[7] = (short)f2bf(a1.w);
#pragma unroll
        for (int ct = 0; ct < 4; ++ct)
            acc[ct] = __builtin_amdgcn_mfma_f32_16x16x32_bf16(af, bfrag[kc][ct], acc[ct], 0, 0, 0);
    }

    float dv[4];
#pragma unroll
    for (int r = 0; r < 4; ++r) {
        int node = node_base + q * 4 + r;
        dv[r] = (node < NNODES) ? dis[node] : 0.f;
    }
#pragma unroll
    for (int ct = 0; ct < 4; ++ct) {
        int col = ct * 16 + m;
#pragma unroll
        for (int r = 0; r < 4; ++r) {
            int node = node_base + q * 4 + r;
            if (node < NNODES)
                hws[(size_t)node * HID + col] = f2bf(acc[ct][r] * dv[r]);
        }
    }
}

// ---------------- gather + epilogue (column-sliced by XCD) ----------------
// Block b: slice = ((b&7)>=4) -> columns [slice*32, slice*32+32) = one 64B
// line of each bf16 row. XCDs 0-3 handle slice 0, XCDs 4-7 slice 1 (b%8 ~ XCD
// round-robin heuristic): each XCD touches only one line per source row.
// Wave = 2 nodes x 32 cols; block of 256 = 8 nodes.
__global__ void gather_update(const ushort* __restrict__ hws,
                              const int* __restrict__ row_ptr, const int* __restrict__ cnt,
                              const int* __restrict__ srcs, const float* __restrict__ dis,
                              const float* __restrict__ bias,
                              const float* __restrict__ g, const float* __restrict__ be,
                              const float* __restrict__ mu, const float* __restrict__ var,
                              const float* __restrict__ last, float* __restrict__ hout) {
    int b = blockIdx.x;
    int slice = (b >> 2) & 1;                       // == ((b&7) >= 4)
    int group = ((b >> 3) << 2) | (b & 3);          // [0, GGROUPS)
    int wave = threadIdx.x >> 6;
    int lane = threadIdx.x & 63;
    int d = group * 8 + wave * 2 + (lane >> 5);
    if (d >= NNODES) return;
    int col = slice * 32 + (lane & 31);

    float acc = bf2f(hws[(size_t)d * HID + col]);   // self-loop
    int start = row_ptr[d];
    int n = cnt[d];
    const int* sp = srcs + start;

    int k = 0;
    for (; k + 3 < n; k += 4) {                     // unroll 4 for load ILP
        int s0 = sp[k + 0], s1 = sp[k + 1], s2 = sp[k + 2], s3 = sp[k + 3];
        float v0 = bf2f(hws[(size_t)s0 * HID + col]);
        float v1 = bf2f(hws[(size_t)s1 * HID + col]);
        float v2 = bf2f(hws[(size_t)s2 * HID + col]);
        float v3 = bf2f(hws[(size_t)s3 * HID + col]);
        acc += v0 + v1 + v2 + v3;
    }
    for (; k < n; ++k) acc += bf2f(hws[(size_t)sp[k] * HID + col]);

    float v = acc * dis[d] + bias[col];
    v = (v - mu[col]) * (g[col] * rsqrtf(var[col] + BN_EPS)) + be[col];
    hout[(size_t)d * HID + col] = fmaxf(v, 0.f) + last[(size_t)d * HID + col];
}

extern "C" void kernel_launch(void* const* d_in, const int* in_sizes, int n_in,
                              void* d_out, int out_size, void* d_ws, size_t ws_size,
                              hipStream_t stream) {
    const float* x      = (const float*)d_in[0];
    const int*   eidx   = (const int*)d_in[1];
    const float* fc_w   = (const float*)d_in[2];
    const float* fc_b   = (const float*)d_in[3];
    const float* conv_w = (const float*)d_in[4];
    const float* conv_b = (const float*)d_in[5];
    const float* bn_g   = (const float*)d_in[6];
    const float* bn_b   = (const float*)d_in[7];
    const float* bn_m   = (const float*)d_in[8];
    const float* bn_v   = (const float*)d_in[9];

    const int* src = eidx;
    const int* dst = eidx + NEDGES;

    float* hio = (float*)d_out;       // serves as h1 (layer-1 out) and final out

    // workspace (4B elems): dis | cnt | row_ptr | pos | bsum | srcs | h0 | hws(bf16)
    float*  dis     = (float*)d_ws;
    int*    cnt     = (int*)(dis + NPAD);
    int*    row_ptr = cnt + NPAD;
    int*    pos     = row_ptr + NPAD;
    int*    bsum    = pos + NPAD;
    int*    srcs    = bsum + 512;
    float*  h0      = (float*)(srcs + NEDGES) + 48;   // re-align; residual `last`
    ushort* hws     = (ushort*)(h0 + (size_t)NNODES * HID);

    const int BLK = 256;
    const int gridN   = (NNODES + BLK - 1) / BLK;
    const int gridF   = FILL_CHUNKS * 8;                 // 4888 (filtered count/fill)
    const int gridGA  = GGROUPS * 2;                     // 25000 (sliced gather)
    const int gridMM  = (NNODES + 63) / 64;              // 1563 (MFMA matmuls)

    // CSR build + degree (dst-range partitioned)
    csr_zero<<<gridN, BLK, 0, stream>>>(cnt);
    csr_count<<<gridF, BLK, 0, stream>>>(dst, cnt);
    scan1<<<NSCAN_BLOCKS, 256, 0, stream>>>(cnt, row_ptr, bsum, dis);
    scan2<<<1, 512, 0, stream>>>(bsum);
    scan3<<<gridN, BLK, 0, stream>>>(row_ptr, bsum, pos);
    csr_fill<<<gridF, BLK, 0, stream>>>(src, dst, pos, srcs);

    // fc + bn0 + relu -> h0 (residual). h0 is never overwritten.
    fc_bn_relu<<<gridMM, BLK, 0, stream>>>(x, fc_w, fc_b, bn_g, bn_b, bn_m, bn_v, h0);

    // layer 1: h0 -> hws -> hio
    conv_mm<<<gridMM, BLK, 0, stream>>>(h0, conv_w, dis, hws);
    gather_update<<<gridGA, BLK, 0, stream>>>(hws, row_ptr, cnt, srcs, dis,
                                              conv_b, bn_g + HID, bn_b + HID,
                                              bn_m + HID, bn_v + HID, h0, hio);

    // layer 2: hio -> hws -> hio (final output)
    conv_mm<<<gridMM, BLK, 0, stream>>>(hio, conv_w + HID * HID, dis, hws);
    gather_update<<<gridGA, BLK, 0, stream>>>(hws, row_ptr, cnt, srcs, dis,
                                              conv_b + HID, bn_g + 2 * HID, bn_b + 2 * HID,
                                              bn_m + 2 * HID, bn_v + 2 * HID, h0, hio);
}